// Round 7
// baseline (309.650 us; speedup 1.0000x reference)
//
#include <hip/hip_runtime.h>
#include <hip/hip_bf16.h>
#include <math.h>

#define B_    2
#define N_    2048
#define DIM_  1024
#define H_    16
#define HD_   64
#define EPS_  1e-5f
#define SCALE_ 0.125f   // HD_^-0.5
#define LOG2E_ 1.4426950408889634f
#define MFIX_  14.0f    // fixed softmax max (log2 domain); |logit| <= 11.7 hard bound

typedef __attribute__((ext_vector_type(8))) __bf16 bf16x8;
typedef __attribute__((ext_vector_type(8))) unsigned short ushort8;
typedef __attribute__((ext_vector_type(4))) float f32x4;

__device__ __forceinline__ unsigned short f2bf(float x) {
    unsigned u = __builtin_bit_cast(unsigned, x);
    u += 0x7fff + ((u >> 16) & 1);   // RNE
    return (unsigned short)(u >> 16);
}
// pack two floats to bf16x2 with round-half-up (+0x8000) via v_perm
__device__ __forceinline__ unsigned pk2bf(float a, float b) {
    unsigned ua = __builtin_bit_cast(unsigned, a) + 0x8000u;
    unsigned ub = __builtin_bit_cast(unsigned, b) + 0x8000u;
    return __builtin_amdgcn_perm(ub, ua, 0x07060302);
}

__device__ __forceinline__ void gl_lds16(const void* g, void* l) {
    __builtin_amdgcn_global_load_lds(
        (const __attribute__((address_space(1))) void*)g,
        (__attribute__((address_space(3))) void*)l, 16, 0, 0);
}

// ---------------------------------------------------------------------------
// Fused fp32 -> bf16 cast of [x | qkv_w | proj_w] into one contiguous region.
// ---------------------------------------------------------------------------
__global__ __launch_bounds__(256) void cast_all_bf16(
    const float* __restrict__ x, const float* __restrict__ qkvw,
    const float* __restrict__ pw, unsigned short* __restrict__ out) {
    int i = (blockIdx.x * 256 + threadIdx.x) * 8;
    const float* src;
    if (i < 4194304) src = x + i;
    else if (i < 7340032) src = qkvw + (i - 4194304);
    else src = pw + (i - 7340032);
    float4 v0 = *(const float4*)src;
    float4 v1 = *(const float4*)(src + 4);
    ushort8 r;
    r[0] = f2bf(v0.x); r[1] = f2bf(v0.y); r[2] = f2bf(v0.z); r[3] = f2bf(v0.w);
    r[4] = f2bf(v1.x); r[5] = f2bf(v1.y); r[6] = f2bf(v1.z); r[7] = f2bf(v1.w);
    *(ushort8*)(out + i) = r;
}

// ---------------------------------------------------------------------------
// Pack int32 mask (B,N,N) -> bitmask (B,N,N/64) uint64. One wave per word.
// ---------------------------------------------------------------------------
__global__ __launch_bounds__(256) void pack_mask(
    const int* __restrict__ mask, unsigned long long* __restrict__ bm) {
    int w = blockIdx.x * 4 + (threadIdx.x >> 6);
    int lane = threadIdx.x & 63;
    int mv = mask[(size_t)w * 64 + lane];
    unsigned long long bits = __ballot(mv != 0);
    if (lane == 0) bm[w] = bits;
}

// ---------------------------------------------------------------------------
// GEMM1 + fused LayerNorm epilogue (unchanged from round 6).
// ---------------------------------------------------------------------------
__global__ __launch_bounds__(256) void gemm_qkv_ln(
    const unsigned short* __restrict__ A, const unsigned short* __restrict__ Bw,
    const float* __restrict__ qnw, const float* __restrict__ qnb,
    const float* __restrict__ knw, const float* __restrict__ knb,
    unsigned short* __restrict__ qbuf, unsigned short* __restrict__ kbuf,
    unsigned short* __restrict__ vbuf) {
    const int K = DIM_;
    __shared__ unsigned short As[128 * 32];
    __shared__ unsigned short Bs[128 * 32];
    const int tid = threadIdx.x;
    const int wave = tid >> 6, lane = tid & 63;
    const int quad = lane >> 4, lcol = lane & 15;
    const int wr = wave >> 1, wc = wave & 1;
    const int row0 = blockIdx.y * 128, col0 = blockIdx.x * 128;

    f32x4 acc[4][4];
#pragma unroll
    for (int i = 0; i < 4; ++i)
#pragma unroll
        for (int j = 0; j < 4; ++j) acc[i][j] = (f32x4){0.f, 0.f, 0.f, 0.f};

    for (int k0 = 0; k0 < K; k0 += 32) {
        __syncthreads();
#pragma unroll
        for (int c = 0; c < 2; ++c) {
            int base = wave * 2048 + c * 1024;
            int myofs = base + lane * 16;
            int r = myofs >> 6;
            int kb = myofs & 63;
            gl_lds16((const char*)A + ((size_t)(row0 + r) * K + k0) * 2 + kb,
                     (char*)As + base);
            gl_lds16((const char*)Bw + ((size_t)(col0 + r) * K + k0) * 2 + kb,
                     (char*)Bs + base);
        }
        __syncthreads();

        bf16x8 af[4], bfr[4];
#pragma unroll
        for (int i = 0; i < 4; ++i) {
            af[i] = *(const bf16x8*)&As[(wr * 64 + i * 16 + lcol) * 32 + quad * 8];
            bfr[i] = *(const bf16x8*)&Bs[(wc * 64 + i * 16 + lcol) * 32 + quad * 8];
        }
#pragma unroll
        for (int i = 0; i < 4; ++i)
#pragma unroll
            for (int j = 0; j < 4; ++j)
                acc[i][j] = __builtin_amdgcn_mfma_f32_16x16x32_bf16(
                    af[i], bfr[j], acc[i][j], 0, 0, 0);
    }

    const int colbase = col0 + wc * 64;      // wave-uniform, one head
    const int t = colbase >> 10;             // 0=q, 1=k, 2=v
    const int h = (colbase & 1023) >> 6;

    if (t < 2) {
        const float* wv = (t == 0) ? qnw : knw;
        const float* bv = (t == 0) ? qnb : knb;
        float wreg[4], breg[4];
#pragma unroll
        for (int j = 0; j < 4; ++j) {
            wreg[j] = wv[j * 16 + lcol];
            breg[j] = bv[j * 16 + lcol];
        }
        const float sc = (t == 0) ? (SCALE_ * LOG2E_) : 1.f;
        unsigned short* obase = (t == 0) ? qbuf : kbuf;
#pragma unroll
        for (int i = 0; i < 4; ++i) {
#pragma unroll
            for (int reg = 0; reg < 4; ++reg) {
                int row = row0 + wr * 64 + i * 16 + quad * 4 + reg;
                int bb = row >> 11, n = row & (N_ - 1);
                float v[4];
#pragma unroll
                for (int j = 0; j < 4; ++j) v[j] = acc[i][j][reg];
                float s = v[0] + v[1] + v[2] + v[3];
                s += __shfl_xor(s, 1);
                s += __shfl_xor(s, 2);
                s += __shfl_xor(s, 4);
                s += __shfl_xor(s, 8);
                float mu = s * (1.f / 64.f);
                float d[4], s2 = 0.f;
#pragma unroll
                for (int j = 0; j < 4; ++j) {
                    d[j] = v[j] - mu;
                    s2 += d[j] * d[j];
                }
                s2 += __shfl_xor(s2, 1);
                s2 += __shfl_xor(s2, 2);
                s2 += __shfl_xor(s2, 4);
                s2 += __shfl_xor(s2, 8);
                float r = rsqrtf(s2 * (1.f / 64.f) + EPS_);
                unsigned short* dst =
                    obase + ((size_t)(bb * H_ + h) * N_ + n) * 64 + lcol;
#pragma unroll
                for (int j = 0; j < 4; ++j)
                    dst[j * 16] = f2bf((d[j] * r * wreg[j] + breg[j]) * sc);
            }
        }
    } else {
        const int dcol = colbase & 1023;
#pragma unroll
        for (int i = 0; i < 4; ++i) {
#pragma unroll
            for (int reg = 0; reg < 4; ++reg) {
                int row = row0 + wr * 64 + i * 16 + quad * 4 + reg;
                unsigned short* dst = vbuf + (size_t)row * DIM_ + dcol + lcol;
#pragma unroll
                for (int j = 0; j < 4; ++j)
                    dst[j * 16] = f2bf(acc[i][j][reg]);
            }
        }
    }
}

// ---------------------------------------------------------------------------
// bf16 MFMA NT GEMM (output projection, unchanged).
// ---------------------------------------------------------------------------
template <int WITH_BIAS, int OUT_BF16>
__global__ __launch_bounds__(256) void gemm_bt_mfma(
    const unsigned short* __restrict__ A, const unsigned short* __restrict__ Bw,
    const float* __restrict__ bias, void* __restrict__ Cout, int M, int Ncols,
    int K) {
    __shared__ unsigned short As[128 * 32];
    __shared__ unsigned short Bs[128 * 32];
    const int tid = threadIdx.x;
    const int wave = tid >> 6, lane = tid & 63;
    const int quad = lane >> 4, lcol = lane & 15;
    const int wr = wave >> 1, wc = wave & 1;
    const int row0 = blockIdx.y * 128, col0 = blockIdx.x * 128;

    f32x4 acc[4][4];
#pragma unroll
    for (int i = 0; i < 4; ++i)
#pragma unroll
        for (int j = 0; j < 4; ++j) acc[i][j] = (f32x4){0.f, 0.f, 0.f, 0.f};

    for (int k0 = 0; k0 < K; k0 += 32) {
        __syncthreads();
#pragma unroll
        for (int c = 0; c < 2; ++c) {
            int base = wave * 2048 + c * 1024;
            int myofs = base + lane * 16;
            int r = myofs >> 6;
            int kb = myofs & 63;
            gl_lds16((const char*)A + ((size_t)(row0 + r) * K + k0) * 2 + kb,
                     (char*)As + base);
            gl_lds16((const char*)Bw + ((size_t)(col0 + r) * K + k0) * 2 + kb,
                     (char*)Bs + base);
        }
        __syncthreads();

        bf16x8 af[4], bfr[4];
#pragma unroll
        for (int i = 0; i < 4; ++i) {
            af[i] = *(const bf16x8*)&As[(wr * 64 + i * 16 + lcol) * 32 + quad * 8];
            bfr[i] = *(const bf16x8*)&Bs[(wc * 64 + i * 16 + lcol) * 32 + quad * 8];
        }
#pragma unroll
        for (int i = 0; i < 4; ++i)
#pragma unroll
            for (int j = 0; j < 4; ++j)
                acc[i][j] = __builtin_amdgcn_mfma_f32_16x16x32_bf16(
                    af[i], bfr[j], acc[i][j], 0, 0, 0);
    }

#pragma unroll
    for (int i = 0; i < 4; ++i) {
#pragma unroll
        for (int j = 0; j < 4; ++j) {
            int col = col0 + wc * 64 + j * 16 + lcol;
            float bv = WITH_BIAS ? bias[col] : 0.f;
#pragma unroll
            for (int reg = 0; reg < 4; ++reg) {
                int row = row0 + wr * 64 + i * 16 + quad * 4 + reg;
                float v = acc[i][j][reg] + bv;
                if (OUT_BF16)
                    ((unsigned short*)Cout)[(size_t)row * Ncols + col] = f2bf(v);
                else
                    ((float*)Cout)[(size_t)row * Ncols + col] = v;
            }
        }
    }
}

// ---------------------------------------------------------------------------
// Extract V (bf16) from vbuf (B,N,H*D), write transposed (B,H,D,N).
// ---------------------------------------------------------------------------
__global__ __launch_bounds__(256) void transpose_v(
    const unsigned short* __restrict__ vbuf, unsigned short* __restrict__ vt) {
    __shared__ unsigned short Ts[64 * 65];
    const int tid = threadIdx.x;
    const int bh = blockIdx.y, n0 = blockIdx.x * 64;
    const int b = bh >> 4, h = bh & 15;
    {
        int r = tid >> 2, s = tid & 3;
        const unsigned short* src =
            vbuf + (size_t)(b * N_ + n0 + r) * DIM_ + h * 64 + s * 16;
#pragma unroll
        for (int i = 0; i < 16; ++i) Ts[r * 65 + s * 16 + i] = src[i];
    }
    __syncthreads();
    {
        int d = tid >> 2, ks = tid & 3;
        __align__(16) unsigned short tmp[16];
#pragma unroll
        for (int i = 0; i < 16; ++i) tmp[i] = Ts[(ks * 16 + i) * 65 + d];
        unsigned short* dst = vt + (size_t)(bh * 64 + d) * N_ + n0 + ks * 16;
        *(int4*)dst = *(const int4*)&tmp[0];
        *(int4*)(dst + 8) = *(const int4*)&tmp[8];
    }
}

// ---------------------------------------------------------------------------
// MFMA flash attention v5: fixed-max softmax + double-buffered staging.
// - q pre-scaled by D^-0.5*log2(e); |logit| <= 11.7 (Cauchy-Schwarz on
//   unit-variance LN outputs) => fixed max MFIX=14, no online max/alpha.
// - mask applied as sacc init (bit ? -1e4 : -MFIX); p = exp2(sacc) direct.
// - l via ones-row MFMA (row-sum of P in the matrix pipe).
// - K/V double-buffered; ONE barrier per iter; prefetch of tile t+1 issued
//   before computing tile t, so the vmcnt drain at the barrier is covered.
// Layouts as v4: S^T=K*Q^T C[key=quad*4+reg][q=lcol]; O^T=V^T*P^T.
// LDS 49.2 KB -> 3 blocks/CU.
// ---------------------------------------------------------------------------
__global__ __launch_bounds__(256) void flash_attn_mfma5(
    const unsigned short* __restrict__ q, const unsigned short* __restrict__ k,
    const unsigned short* __restrict__ vt,
    const unsigned long long* __restrict__ bm, unsigned short* __restrict__ ao) {
    __shared__ unsigned short Qs[64 * 64];        // 8 KB
    __shared__ unsigned short Ks[2][64 * 64];     // 16 KB, 8 planes/buf
    __shared__ unsigned short Vts[2][64 * 64];    // 16 KB, 8 planes/buf
    __shared__ unsigned short Ps[4][16 * 72];     // 9 KB wave-private

    const int tid = threadIdx.x;
    const int wave = tid >> 6, lane = tid & 63;
    const int quad = lane >> 4, lcol = lane & 15;
    const int bh = blockIdx.y, b = bh >> 4, h = bh & 15;
    const int q0 = blockIdx.x * 64;

    const char* kgbase = (const char*)k + (size_t)bh * N_ * 128;
    const char* vtbase = (const char*)vt + (size_t)bh * 64 * N_ * 2;

    // per-lane staging pointers (advance by constants each tile)
    const char* kp[2];
    const char* vp[2];
#pragma unroll
    for (int ci = 0; ci < 2; ++ci) {
        int c = wave * 2 + ci;
        int swz = (c & 3) * 2;
        kp[ci] = kgbase + (size_t)(lane ^ swz) * 128 + c * 16;
        vp[ci] = vtbase + ((size_t)(lane ^ swz) * N_ + c * 8) * 2;
    }

    // ---- prologue: stage Q + K/V tile 0 into buf 0 ----
    {
        const char* qg = (const char*)(q + (size_t)(bh * N_ + q0) * 64);
#pragma unroll
        for (int c = 0; c < 2; ++c) {
            int base = wave * 2048 + c * 1024;
            gl_lds16(qg + base + lane * 16, (char*)Qs + base);
        }
#pragma unroll
        for (int ci = 0; ci < 2; ++ci) {
            int c = wave * 2 + ci;
            gl_lds16(kp[ci], (char*)Ks[0] + c * 1024);
            gl_lds16(vp[ci], (char*)Vts[0] + c * 1024);
            kp[ci] += 64 * 128;   // next 64 keys
            vp[ci] += 64 * 2;
        }
    }
    const unsigned long long* bmq =
        bm + ((size_t)b * N_ + q0 + wave * 16 + lcol) * 32;
    unsigned long long mw_next = bmq[0];
    __syncthreads();  // Q + tile0 resident

    bf16x8 bq[2];
#pragma unroll
    for (int d0 = 0; d0 < 2; ++d0)
        bq[d0] = *(const bf16x8*)&Qs[(wave * 16 + lcol) * 64 + d0 * 32 + quad * 8];

    ushort8 ot;
#pragma unroll
    for (int i = 0; i < 8; ++i) ot[i] = 0x3F80;  // bf16 1.0
    const bf16x8 ones = __builtin_bit_cast(bf16x8, ot);

    f32x4 oacc[4];
#pragma unroll
    for (int dt = 0; dt < 4; ++dt) oacc[dt] = (f32x4){0.f, 0.f, 0.f, 0.f};
    f32x4 lacc = (f32x4){0.f, 0.f, 0.f, 0.f};

    for (int k0 = 0; k0 < N_; k0 += 64) {
        const int cur = (k0 >> 6) & 1;
        const unsigned long long mw = mw_next;
        // ---- prefetch tile t+1 into the other buffer (no wait) ----
        if (k0 + 64 < N_) {
#pragma unroll
            for (int ci = 0; ci < 2; ++ci) {
                int c = wave * 2 + ci;
                gl_lds16(kp[ci], (char*)Ks[cur ^ 1] + c * 1024);
                gl_lds16(vp[ci], (char*)Vts[cur ^ 1] + c * 1024);
                kp[ci] += 64 * 128;
                vp[ci] += 64 * 2;
            }
            mw_next = bmq[(k0 >> 6) + 1];
        }

        // ---- sacc init from mask: masked -> -1e4, else -MFIX ----
        unsigned long long mq = mw >> (quad * 4);
        unsigned mlo = (unsigned)mq, mhi = (unsigned)(mq >> 32);
        f32x4 sacc[4];
#pragma unroll
        for (int kt = 0; kt < 4; ++kt) {
            unsigned word = (kt < 2) ? mlo : mhi;
            const int sh = (kt & 1) * 16;
#pragma unroll
            for (int reg = 0; reg < 4; ++reg)
                sacc[kt][reg] = ((word >> (sh + reg)) & 1u) ? -1e4f : -MFIX_;
        }

        // ---- S^T = K Q^T (on top of mask-bias init) ----
        const char* ksb = (const char*)Ks[cur];
        const char* vsb = (const char*)Vts[cur];
#pragma unroll
        for (int kt = 0; kt < 4; ++kt) {
#pragma unroll
            for (int d0 = 0; d0 < 2; ++d0) {
                int p = d0 * 4 + quad;
                bf16x8 ak = *(const bf16x8*)(ksb + p * 1024 +
                                             (((kt * 16 + lcol) ^ (quad * 2)) << 4));
                sacc[kt] = __builtin_amdgcn_mfma_f32_16x16x32_bf16(
                    ak, bq[d0], sacc[kt], 0, 0, 0);
            }
        }

        // ---- p = exp2(s) (max already folded), pack to Ps ----
#pragma unroll
        for (int kt = 0; kt < 4; ++kt) {
            float p0 = exp2f(sacc[kt][0]);
            float p1 = exp2f(sacc[kt][1]);
            float p2 = exp2f(sacc[kt][2]);
            float p3 = exp2f(sacc[kt][3]);
            uint2 pk;
            pk.x = pk2bf(p0, p1);
            pk.y = pk2bf(p2, p3);
            *(uint2*)&Ps[wave][lcol * 72 + kt * 16 + quad * 4] = pk;
        }

        // ---- O^T += V^T P^T ; l += ones*P^T (wave-private Ps, no barrier) ----
#pragma unroll
        for (int k2 = 0; k2 < 2; ++k2) {
            bf16x8 pf =
                *(const bf16x8*)&Ps[wave][lcol * 72 + k2 * 32 + quad * 8];
            lacc = __builtin_amdgcn_mfma_f32_16x16x32_bf16(ones, pf, lacc,
                                                           0, 0, 0);
#pragma unroll
            for (int dt = 0; dt < 4; ++dt) {
                int p = k2 * 4 + quad;
                bf16x8 vf = *(const bf16x8*)(vsb + p * 1024 +
                                             (((dt * 16 + lcol) ^ (quad * 2)) << 4));
                oacc[dt] = __builtin_amdgcn_mfma_f32_16x16x32_bf16(
                    vf, pf, oacc[dt], 0, 0, 0);
            }
        }
        __syncthreads();  // all waves done with buf[cur]; prefetch drained
    }

    // ---- epilogue: /l, store bf16 (B,N,C) ----
    float inv = 1.f / lacc[0];  // rows of lacc all equal = l(query=lcol)
    int row = q0 + wave * 16 + lcol;
    unsigned short* dst = ao + ((size_t)(b * N_ + row)) * DIM_ + h * 64 + quad * 4;
#pragma unroll
    for (int dt = 0; dt < 4; ++dt) {
        uint2 pk;
        pk.x = pk2bf(oacc[dt][0] * inv, oacc[dt][1] * inv);
        pk.y = pk2bf(oacc[dt][2] * inv, oacc[dt][3] * inv);
        *(uint2*)(dst + dt * 16) = pk;
    }
}

// ---------------------------------------------------------------------------
extern "C" void kernel_launch(void* const* d_in, const int* in_sizes, int n_in,
                              void* d_out, int out_size, void* d_ws,
                              size_t ws_size, hipStream_t stream) {
    const float* x     = (const float*)d_in[0];
    const int*   mask  = (const int*)d_in[1];
    const float* qkv_w = (const float*)d_in[2];
    const float* qnw   = (const float*)d_in[3];
    const float* qnb   = (const float*)d_in[4];
    const float* knw   = (const float*)d_in[5];
    const float* knb   = (const float*)d_in[6];
    const float* pw    = (const float*)d_in[7];
    const float* pb    = (const float*)d_in[8];
    float* out = (float*)d_out;

    // workspace layout (bytes) — 51.4 MB total
    char* ws = (char*)d_ws;
    unsigned short* x_bf  = (unsigned short*)(ws + 0);          // 8.39 MB
    unsigned short* qw_bf = (unsigned short*)(ws + 8388608);    // 6.29 MB
    unsigned short* pw_bf = (unsigned short*)(ws + 14680064);   // 2.10 MB
    unsigned short* qbuf  = (unsigned short*)(ws + 16777216);   // 8.39 MB
    unsigned short* kbuf  = (unsigned short*)(ws + 25165824);   // 8.39 MB
    unsigned short* vbuf  = (unsigned short*)(ws + 33554432);   // 8.39 MB
    unsigned short* vt    = (unsigned short*)(ws + 41943040);   // 8.39 MB
    unsigned long long* bmask = (unsigned long long*)(ws + 50331648);  // 1 MB
    unsigned short* ao_bnc = vbuf;  // alias: vbuf dead after transpose_v

    // 0) fused casts -> contiguous [x_bf | qw_bf | pw_bf]
    cast_all_bf16<<<8388608 / 2048, 256, 0, stream>>>(x, qkv_w, pw, x_bf);

    // 1) GEMM1 + fused LN epilogue -> qbuf/kbuf (B,H,N,D), vbuf (B,N,HD)
    gemm_qkv_ln<<<dim3(3072 / 128, 4096 / 128), 256, 0, stream>>>(
        x_bf, qw_bf, qnw, qnb, knw, knb, qbuf, kbuf, vbuf);

    // 2) v -> bf16 transposed (B,H,D,N)
    transpose_v<<<dim3(N_ / 64, B_ * H_), 256, 0, stream>>>(vbuf, vt);

    // 2b) pack mask to bits
    pack_mask<<<(B_ * N_ * (N_ / 64)) / 4, 256, 0, stream>>>(mask, bmask);

    // 3) masked flash attention v5 -> ao bf16 (B,N,C)
    flash_attn_mfma5<<<dim3(N_ / 64, B_ * H_), 256, 0, stream>>>(
        qbuf, kbuf, vt, bmask, ao_bnc);

    // 4) out = ao @ proj_w^T + proj_b (bf16 MFMA, fp32 out)
    gemm_bt_mfma<1, 0><<<dim3(DIM_ / 128, 4096 / 128), 256, 0, stream>>>(
        ao_bnc, pw_bf, pb, out, B_ * N_, DIM_, DIM_);
}

// Round 8
// 293.469 us; speedup vs baseline: 1.0551x; 1.0551x over previous
//
#include <hip/hip_runtime.h>
#include <hip/hip_bf16.h>
#include <math.h>

#define B_    2
#define N_    2048
#define DIM_  1024
#define H_    16
#define HD_   64
#define EPS_  1e-5f
#define SCALE_ 0.125f   // HD_^-0.5
#define LOG2E_ 1.4426950408889634f
#define MFIX_  14.0f    // fixed softmax max (log2 domain); |logit| <= 11.7 hard bound

typedef __attribute__((ext_vector_type(8))) __bf16 bf16x8;
typedef __attribute__((ext_vector_type(8))) unsigned short ushort8;
typedef __attribute__((ext_vector_type(4))) float f32x4;
typedef __attribute__((ext_vector_type(4))) unsigned int uint4v;

__device__ __forceinline__ unsigned short f2bf(float x) {
    unsigned u = __builtin_bit_cast(unsigned, x);
    u += 0x7fff + ((u >> 16) & 1);   // RNE
    return (unsigned short)(u >> 16);
}
// pack two floats to bf16x2 with round-half-up (+0x8000) via v_perm
__device__ __forceinline__ unsigned pk2bf(float a, float b) {
    unsigned ua = __builtin_bit_cast(unsigned, a) + 0x8000u;
    unsigned ub = __builtin_bit_cast(unsigned, b) + 0x8000u;
    return __builtin_amdgcn_perm(ub, ua, 0x07060302);
}

__device__ __forceinline__ void gl_lds16(const void* g, void* l) {
    __builtin_amdgcn_global_load_lds(
        (const __attribute__((address_space(1))) void*)g,
        (__attribute__((address_space(3))) void*)l, 16, 0, 0);
}

// ---------------------------------------------------------------------------
// Fused fp32 -> bf16 cast of [x | qkv_w | proj_w] into one contiguous region.
// ---------------------------------------------------------------------------
__global__ __launch_bounds__(256) void cast_all_bf16(
    const float* __restrict__ x, const float* __restrict__ qkvw,
    const float* __restrict__ pw, unsigned short* __restrict__ out) {
    int i = (blockIdx.x * 256 + threadIdx.x) * 8;
    const float* src;
    if (i < 4194304) src = x + i;
    else if (i < 7340032) src = qkvw + (i - 4194304);
    else src = pw + (i - 7340032);
    float4 v0 = *(const float4*)src;
    float4 v1 = *(const float4*)(src + 4);
    ushort8 r;
    r[0] = f2bf(v0.x); r[1] = f2bf(v0.y); r[2] = f2bf(v0.z); r[3] = f2bf(v0.w);
    r[4] = f2bf(v1.x); r[5] = f2bf(v1.y); r[6] = f2bf(v1.z); r[7] = f2bf(v1.w);
    *(ushort8*)(out + i) = r;
}

// ---------------------------------------------------------------------------
// Pack int32 mask (B,N,N) -> bitmask (B,N,N/64) uint64. One wave per word.
// ---------------------------------------------------------------------------
__global__ __launch_bounds__(256) void pack_mask(
    const int* __restrict__ mask, unsigned long long* __restrict__ bm) {
    int w = blockIdx.x * 4 + (threadIdx.x >> 6);
    int lane = threadIdx.x & 63;
    int mv = mask[(size_t)w * 64 + lane];
    unsigned long long bits = __ballot(mv != 0);
    if (lane == 0) bm[w] = bits;
}

// ---------------------------------------------------------------------------
// GEMM1 + fused LayerNorm epilogue (unchanged from round 6).
// ---------------------------------------------------------------------------
__global__ __launch_bounds__(256) void gemm_qkv_ln(
    const unsigned short* __restrict__ A, const unsigned short* __restrict__ Bw,
    const float* __restrict__ qnw, const float* __restrict__ qnb,
    const float* __restrict__ knw, const float* __restrict__ knb,
    unsigned short* __restrict__ qbuf, unsigned short* __restrict__ kbuf,
    unsigned short* __restrict__ vbuf) {
    const int K = DIM_;
    __shared__ unsigned short As[128 * 32];
    __shared__ unsigned short Bs[128 * 32];
    const int tid = threadIdx.x;
    const int wave = tid >> 6, lane = tid & 63;
    const int quad = lane >> 4, lcol = lane & 15;
    const int wr = wave >> 1, wc = wave & 1;
    const int row0 = blockIdx.y * 128, col0 = blockIdx.x * 128;

    f32x4 acc[4][4];
#pragma unroll
    for (int i = 0; i < 4; ++i)
#pragma unroll
        for (int j = 0; j < 4; ++j) acc[i][j] = (f32x4){0.f, 0.f, 0.f, 0.f};

    for (int k0 = 0; k0 < K; k0 += 32) {
        __syncthreads();
#pragma unroll
        for (int c = 0; c < 2; ++c) {
            int base = wave * 2048 + c * 1024;
            int myofs = base + lane * 16;
            int r = myofs >> 6;
            int kb = myofs & 63;
            gl_lds16((const char*)A + ((size_t)(row0 + r) * K + k0) * 2 + kb,
                     (char*)As + base);
            gl_lds16((const char*)Bw + ((size_t)(col0 + r) * K + k0) * 2 + kb,
                     (char*)Bs + base);
        }
        __syncthreads();

        bf16x8 af[4], bfr[4];
#pragma unroll
        for (int i = 0; i < 4; ++i) {
            af[i] = *(const bf16x8*)&As[(wr * 64 + i * 16 + lcol) * 32 + quad * 8];
            bfr[i] = *(const bf16x8*)&Bs[(wc * 64 + i * 16 + lcol) * 32 + quad * 8];
        }
#pragma unroll
        for (int i = 0; i < 4; ++i)
#pragma unroll
            for (int j = 0; j < 4; ++j)
                acc[i][j] = __builtin_amdgcn_mfma_f32_16x16x32_bf16(
                    af[i], bfr[j], acc[i][j], 0, 0, 0);
    }

    const int colbase = col0 + wc * 64;      // wave-uniform, one head
    const int t = colbase >> 10;             // 0=q, 1=k, 2=v
    const int h = (colbase & 1023) >> 6;

    if (t < 2) {
        const float* wv = (t == 0) ? qnw : knw;
        const float* bv = (t == 0) ? qnb : knb;
        float wreg[4], breg[4];
#pragma unroll
        for (int j = 0; j < 4; ++j) {
            wreg[j] = wv[j * 16 + lcol];
            breg[j] = bv[j * 16 + lcol];
        }
        const float sc = (t == 0) ? (SCALE_ * LOG2E_) : 1.f;
        unsigned short* obase = (t == 0) ? qbuf : kbuf;
#pragma unroll
        for (int i = 0; i < 4; ++i) {
#pragma unroll
            for (int reg = 0; reg < 4; ++reg) {
                int row = row0 + wr * 64 + i * 16 + quad * 4 + reg;
                int bb = row >> 11, n = row & (N_ - 1);
                float v[4];
#pragma unroll
                for (int j = 0; j < 4; ++j) v[j] = acc[i][j][reg];
                float s = v[0] + v[1] + v[2] + v[3];
                s += __shfl_xor(s, 1);
                s += __shfl_xor(s, 2);
                s += __shfl_xor(s, 4);
                s += __shfl_xor(s, 8);
                float mu = s * (1.f / 64.f);
                float d[4], s2 = 0.f;
#pragma unroll
                for (int j = 0; j < 4; ++j) {
                    d[j] = v[j] - mu;
                    s2 += d[j] * d[j];
                }
                s2 += __shfl_xor(s2, 1);
                s2 += __shfl_xor(s2, 2);
                s2 += __shfl_xor(s2, 4);
                s2 += __shfl_xor(s2, 8);
                float r = rsqrtf(s2 * (1.f / 64.f) + EPS_);
                unsigned short* dst =
                    obase + ((size_t)(bb * H_ + h) * N_ + n) * 64 + lcol;
#pragma unroll
                for (int j = 0; j < 4; ++j)
                    dst[j * 16] = f2bf((d[j] * r * wreg[j] + breg[j]) * sc);
            }
        }
    } else {
        const int dcol = colbase & 1023;
#pragma unroll
        for (int i = 0; i < 4; ++i) {
#pragma unroll
            for (int reg = 0; reg < 4; ++reg) {
                int row = row0 + wr * 64 + i * 16 + quad * 4 + reg;
                unsigned short* dst = vbuf + (size_t)row * DIM_ + dcol + lcol;
#pragma unroll
                for (int j = 0; j < 4; ++j)
                    dst[j * 16] = f2bf(acc[i][j][reg]);
            }
        }
    }
}

// ---------------------------------------------------------------------------
// bf16 MFMA NT GEMM (output projection, unchanged).
// ---------------------------------------------------------------------------
template <int WITH_BIAS, int OUT_BF16>
__global__ __launch_bounds__(256) void gemm_bt_mfma(
    const unsigned short* __restrict__ A, const unsigned short* __restrict__ Bw,
    const float* __restrict__ bias, void* __restrict__ Cout, int M, int Ncols,
    int K) {
    __shared__ unsigned short As[128 * 32];
    __shared__ unsigned short Bs[128 * 32];
    const int tid = threadIdx.x;
    const int wave = tid >> 6, lane = tid & 63;
    const int quad = lane >> 4, lcol = lane & 15;
    const int wr = wave >> 1, wc = wave & 1;
    const int row0 = blockIdx.y * 128, col0 = blockIdx.x * 128;

    f32x4 acc[4][4];
#pragma unroll
    for (int i = 0; i < 4; ++i)
#pragma unroll
        for (int j = 0; j < 4; ++j) acc[i][j] = (f32x4){0.f, 0.f, 0.f, 0.f};

    for (int k0 = 0; k0 < K; k0 += 32) {
        __syncthreads();
#pragma unroll
        for (int c = 0; c < 2; ++c) {
            int base = wave * 2048 + c * 1024;
            int myofs = base + lane * 16;
            int r = myofs >> 6;
            int kb = myofs & 63;
            gl_lds16((const char*)A + ((size_t)(row0 + r) * K + k0) * 2 + kb,
                     (char*)As + base);
            gl_lds16((const char*)Bw + ((size_t)(col0 + r) * K + k0) * 2 + kb,
                     (char*)Bs + base);
        }
        __syncthreads();

        bf16x8 af[4], bfr[4];
#pragma unroll
        for (int i = 0; i < 4; ++i) {
            af[i] = *(const bf16x8*)&As[(wr * 64 + i * 16 + lcol) * 32 + quad * 8];
            bfr[i] = *(const bf16x8*)&Bs[(wc * 64 + i * 16 + lcol) * 32 + quad * 8];
        }
#pragma unroll
        for (int i = 0; i < 4; ++i)
#pragma unroll
            for (int j = 0; j < 4; ++j)
                acc[i][j] = __builtin_amdgcn_mfma_f32_16x16x32_bf16(
                    af[i], bfr[j], acc[i][j], 0, 0, 0);
    }

#pragma unroll
    for (int i = 0; i < 4; ++i) {
#pragma unroll
        for (int j = 0; j < 4; ++j) {
            int col = col0 + wc * 64 + j * 16 + lcol;
            float bv = WITH_BIAS ? bias[col] : 0.f;
#pragma unroll
            for (int reg = 0; reg < 4; ++reg) {
                int row = row0 + wr * 64 + i * 16 + quad * 4 + reg;
                float v = acc[i][j][reg] + bv;
                if (OUT_BF16)
                    ((unsigned short*)Cout)[(size_t)row * Ncols + col] = f2bf(v);
                else
                    ((float*)Cout)[(size_t)row * Ncols + col] = v;
            }
        }
    }
}

// ---------------------------------------------------------------------------
// Extract V (bf16) from vbuf (B,N,H*D), write transposed (B,H,D,N) with
// PV-ready key permutation within each 64-key tile:
//   sigma-position P*32 + q*8 + t*4 + j  <->  key (2P+t)*16 + q*4 + j
// so one b128 LDS read per (dt, kt-pair) is exactly an MFMA A-fragment.
// ---------------------------------------------------------------------------
__global__ __launch_bounds__(256) void transpose_v(
    const unsigned short* __restrict__ vbuf, unsigned short* __restrict__ vt) {
    __shared__ unsigned short Ts[64 * 65];
    const int tid = threadIdx.x;
    const int bh = blockIdx.y, n0 = blockIdx.x * 64;
    const int b = bh >> 4, h = bh & 15;
    {
        int r = tid >> 2, s = tid & 3;
        const unsigned short* src =
            vbuf + (size_t)(b * N_ + n0 + r) * DIM_ + h * 64 + s * 16;
#pragma unroll
        for (int i = 0; i < 16; ++i) Ts[r * 65 + s * 16 + i] = src[i];
    }
    __syncthreads();
    {
        int d = tid >> 2, kt = tid & 3;  // 16 keys = one kt tile
        unsigned short* dstrow = vt + (size_t)(bh * 64 + d) * N_ + n0;
        int P = kt >> 1, t = kt & 1;
#pragma unroll
        for (int q = 0; q < 4; ++q) {
            __align__(8) unsigned short tmp4[4];
#pragma unroll
            for (int j = 0; j < 4; ++j)
                tmp4[j] = Ts[(kt * 16 + q * 4 + j) * 65 + d];
            *(uint2*)(dstrow + P * 32 + q * 8 + t * 4) = *(const uint2*)tmp4;
        }
    }
}

// ---------------------------------------------------------------------------
// MFMA flash attention v6: P stays in registers (no Ps LDS round trip).
// - S^T = K Q^T -> C[key=quad*4+reg][query=lcol]: lane (q,lcol) holds P for
//   its OWN query (lcol) at quad-local keys -> directly usable as the
//   16x16x32 B-operand B[n=lcol][k=quad*8+j], with V's key order permuted
//   (sigma, see transpose_v) so A = one b128 read per (dt, kt-pair).
// - fixed-max softmax (MFIX), mask as sacc init, l via ones-A MFMA.
// - K/V double-buffered, single barrier per iter (v5 mechanics).
// LDS 40 KB -> 4 blocks/CU (16 waves).
// ---------------------------------------------------------------------------
__global__ __launch_bounds__(256) void flash_attn_mfma6(
    const unsigned short* __restrict__ q, const unsigned short* __restrict__ k,
    const unsigned short* __restrict__ vt,
    const unsigned long long* __restrict__ bm, unsigned short* __restrict__ ao) {
    __shared__ unsigned short Qs[64 * 64];        // 8 KB
    __shared__ unsigned short Ks[2][64 * 64];     // 16 KB, 8 planes/buf
    __shared__ unsigned short Vts[2][64 * 64];    // 16 KB, 8 planes/buf

    const int tid = threadIdx.x;
    const int wave = tid >> 6, lane = tid & 63;
    const int quad = lane >> 4, lcol = lane & 15;
    const int bh = blockIdx.y, b = bh >> 4, h = bh & 15;
    const int q0 = blockIdx.x * 64;

    const char* kgbase = (const char*)k + (size_t)bh * N_ * 128;
    const char* vtbase = (const char*)vt + (size_t)bh * 64 * N_ * 2;

    // per-lane staging pointers
    const char* kp[2];
    const char* vp[2];
#pragma unroll
    for (int ci = 0; ci < 2; ++ci) {
        int c = wave * 2 + ci;
        int swz = (c & 3) * 2;
        kp[ci] = kgbase + (size_t)(lane ^ swz) * 128 + c * 16;
        vp[ci] = vtbase + (size_t)(lane ^ swz) * N_ * 2 + c * 16;
    }

    // ---- prologue: stage Q + K/V tile 0 into buf 0 ----
    {
        const char* qg = (const char*)(q + (size_t)(bh * N_ + q0) * 64);
#pragma unroll
        for (int c = 0; c < 2; ++c) {
            int base = wave * 2048 + c * 1024;
            gl_lds16(qg + base + lane * 16, (char*)Qs + base);
        }
#pragma unroll
        for (int ci = 0; ci < 2; ++ci) {
            int c = wave * 2 + ci;
            gl_lds16(kp[ci], (char*)Ks[0] + c * 1024);
            gl_lds16(vp[ci], (char*)Vts[0] + c * 1024);
            kp[ci] += 64 * 128;   // next 64-key tile (128 B per row-tile)
            vp[ci] += 64 * 2;
        }
    }
    const unsigned long long* bmq =
        bm + ((size_t)b * N_ + q0 + wave * 16 + lcol) * 32;
    unsigned long long mw_next = bmq[0];
    __syncthreads();  // Q + tile0 resident

    bf16x8 bq[2];
#pragma unroll
    for (int d0 = 0; d0 < 2; ++d0)
        bq[d0] = *(const bf16x8*)&Qs[(wave * 16 + lcol) * 64 + d0 * 32 + quad * 8];

    ushort8 ot;
#pragma unroll
    for (int i = 0; i < 8; ++i) ot[i] = 0x3F80;  // bf16 1.0
    const bf16x8 ones = __builtin_bit_cast(bf16x8, ot);

    f32x4 oacc[4];
#pragma unroll
    for (int dt = 0; dt < 4; ++dt) oacc[dt] = (f32x4){0.f, 0.f, 0.f, 0.f};
    f32x4 lacc = (f32x4){0.f, 0.f, 0.f, 0.f};

    for (int k0 = 0; k0 < N_; k0 += 64) {
        const int cur = (k0 >> 6) & 1;
        const unsigned long long mw = mw_next;
        // ---- prefetch tile t+1 into the other buffer (no wait) ----
        if (k0 + 64 < N_) {
#pragma unroll
            for (int ci = 0; ci < 2; ++ci) {
                int c = wave * 2 + ci;
                gl_lds16(kp[ci], (char*)Ks[cur ^ 1] + c * 1024);
                gl_lds16(vp[ci], (char*)Vts[cur ^ 1] + c * 1024);
                kp[ci] += 64 * 128;
                vp[ci] += 64 * 2;
            }
            mw_next = bmq[(k0 >> 6) + 1];
        }

        // ---- sacc init from mask: masked -> -1e4, else -MFIX ----
        unsigned long long mq = mw >> (quad * 4);
        unsigned mlo = (unsigned)mq, mhi = (unsigned)(mq >> 32);
        f32x4 sacc[4];
#pragma unroll
        for (int kt = 0; kt < 4; ++kt) {
            unsigned word = (kt < 2) ? mlo : mhi;
            const int sh = (kt & 1) * 16;
#pragma unroll
            for (int reg = 0; reg < 4; ++reg)
                sacc[kt][reg] = ((word >> (sh + reg)) & 1u) ? -1e4f : -MFIX_;
        }

        // ---- S^T = K Q^T (on top of mask-bias init) ----
        const char* ksb = (const char*)Ks[cur];
        const char* vsb = (const char*)Vts[cur];
#pragma unroll
        for (int kt = 0; kt < 4; ++kt) {
#pragma unroll
            for (int d0 = 0; d0 < 2; ++d0) {
                int p = d0 * 4 + quad;
                bf16x8 ak = *(const bf16x8*)(ksb + p * 1024 +
                                             (((kt * 16 + lcol) ^ (quad * 2)) << 4));
                sacc[kt] = __builtin_amdgcn_mfma_f32_16x16x32_bf16(
                    ak, bq[d0], sacc[kt], 0, 0, 0);
            }
        }

        // ---- p = exp2(s), pack into per-kt dword pairs (registers only) ----
        uint2 pk[4];
#pragma unroll
        for (int kt = 0; kt < 4; ++kt) {
            float p0 = exp2f(sacc[kt][0]);
            float p1 = exp2f(sacc[kt][1]);
            float p2 = exp2f(sacc[kt][2]);
            float p3 = exp2f(sacc[kt][3]);
            pk[kt].x = pk2bf(p0, p1);
            pk[kt].y = pk2bf(p2, p3);
        }

        // ---- O^T += V^T P^T ; l += ones*P^T — B straight from registers ----
#pragma unroll
        for (int P = 0; P < 2; ++P) {
            uint4v bu;
            bu[0] = pk[2 * P].x;
            bu[1] = pk[2 * P].y;
            bu[2] = pk[2 * P + 1].x;
            bu[3] = pk[2 * P + 1].y;
            bf16x8 bp = __builtin_bit_cast(bf16x8, bu);
            lacc = __builtin_amdgcn_mfma_f32_16x16x32_bf16(ones, bp, lacc,
                                                           0, 0, 0);
#pragma unroll
            for (int dt = 0; dt < 4; ++dt) {
                int c = P * 4 + quad;  // sigma chunk: positions P*32 + quad*8 ..
                bf16x8 va = *(const bf16x8*)(vsb + c * 1024 +
                                             (((dt * 16 + lcol) ^ (quad * 2)) << 4));
                oacc[dt] = __builtin_amdgcn_mfma_f32_16x16x32_bf16(
                    va, bp, oacc[dt], 0, 0, 0);
            }
        }
        __syncthreads();  // all waves done with buf[cur]; prefetch drained
    }

    // ---- epilogue: /l, store bf16 (B,N,C) ----
    float inv = 1.f / lacc[0];  // rows of lacc all equal = l(query=lcol)
    int row = q0 + wave * 16 + lcol;
    unsigned short* dst = ao + ((size_t)(b * N_ + row)) * DIM_ + h * 64 + quad * 4;
#pragma unroll
    for (int dt = 0; dt < 4; ++dt) {
        uint2 pko;
        pko.x = pk2bf(oacc[dt][0] * inv, oacc[dt][1] * inv);
        pko.y = pk2bf(oacc[dt][2] * inv, oacc[dt][3] * inv);
        *(uint2*)(dst + dt * 16) = pko;
    }
}

// ---------------------------------------------------------------------------
extern "C" void kernel_launch(void* const* d_in, const int* in_sizes, int n_in,
                              void* d_out, int out_size, void* d_ws,
                              size_t ws_size, hipStream_t stream) {
    const float* x     = (const float*)d_in[0];
    const int*   mask  = (const int*)d_in[1];
    const float* qkv_w = (const float*)d_in[2];
    const float* qnw   = (const float*)d_in[3];
    const float* qnb   = (const float*)d_in[4];
    const float* knw   = (const float*)d_in[5];
    const float* knb   = (const float*)d_in[6];
    const float* pw    = (const float*)d_in[7];
    const float* pb    = (const float*)d_in[8];
    float* out = (float*)d_out;

    // workspace layout (bytes) — 51.4 MB total
    char* ws = (char*)d_ws;
    unsigned short* x_bf  = (unsigned short*)(ws + 0);          // 8.39 MB
    unsigned short* qw_bf = (unsigned short*)(ws + 8388608);    // 6.29 MB
    unsigned short* pw_bf = (unsigned short*)(ws + 14680064);   // 2.10 MB
    unsigned short* qbuf  = (unsigned short*)(ws + 16777216);   // 8.39 MB
    unsigned short* kbuf  = (unsigned short*)(ws + 25165824);   // 8.39 MB
    unsigned short* vbuf  = (unsigned short*)(ws + 33554432);   // 8.39 MB
    unsigned short* vt    = (unsigned short*)(ws + 41943040);   // 8.39 MB
    unsigned long long* bmask = (unsigned long long*)(ws + 50331648);  // 1 MB
    unsigned short* ao_bnc = vbuf;  // alias: vbuf dead after transpose_v

    // 0) fused casts -> contiguous [x_bf | qw_bf | pw_bf]
    cast_all_bf16<<<8388608 / 2048, 256, 0, stream>>>(x, qkv_w, pw, x_bf);

    // 1) GEMM1 + fused LN epilogue -> qbuf/kbuf (B,H,N,D), vbuf (B,N,HD)
    gemm_qkv_ln<<<dim3(3072 / 128, 4096 / 128), 256, 0, stream>>>(
        x_bf, qw_bf, qnw, qnb, knw, knb, qbuf, kbuf, vbuf);

    // 2) v -> bf16 transposed + sigma-permuted (B,H,D,N)
    transpose_v<<<dim3(N_ / 64, B_ * H_), 256, 0, stream>>>(vbuf, vt);

    // 2b) pack mask to bits
    pack_mask<<<(B_ * N_ * (N_ / 64)) / 4, 256, 0, stream>>>(mask, bmask);

    // 3) masked flash attention v6 -> ao bf16 (B,N,C)
    flash_attn_mfma6<<<dim3(N_ / 64, B_ * H_), 256, 0, stream>>>(
        qbuf, kbuf, vt, bmask, ao_bnc);

    // 4) out = ao @ proj_w^T + proj_b (bf16 MFMA, fp32 out)
    gemm_bt_mfma<1, 0><<<dim3(DIM_ / 128, 4096 / 128), 256, 0, stream>>>(
        ao_bnc, pw_bf, pb, out, B_ * N_, DIM_, DIM_);
}

// Round 9
// 292.091 us; speedup vs baseline: 1.0601x; 1.0047x over previous
//
#include <hip/hip_runtime.h>
#include <hip/hip_bf16.h>
#include <math.h>

#define B_    2
#define N_    2048
#define DIM_  1024
#define H_    16
#define HD_   64
#define EPS_  1e-5f
#define SCALE_ 0.125f   // HD_^-0.5
#define LOG2E_ 1.4426950408889634f
#define MFIX_  14.0f    // fixed softmax max (log2 domain); |logit| <= 11.7 hard bound

typedef __attribute__((ext_vector_type(8))) __bf16 bf16x8;
typedef __attribute__((ext_vector_type(8))) unsigned short ushort8;
typedef __attribute__((ext_vector_type(4))) float f32x4;
typedef __attribute__((ext_vector_type(4))) unsigned int uint4v;

__device__ __forceinline__ unsigned short f2bf(float x) {
    unsigned u = __builtin_bit_cast(unsigned, x);
    u += 0x7fff + ((u >> 16) & 1);   // RNE
    return (unsigned short)(u >> 16);
}
// pack two floats to bf16x2 with round-half-up (+0x8000) via v_perm
__device__ __forceinline__ unsigned pk2bf(float a, float b) {
    unsigned ua = __builtin_bit_cast(unsigned, a) + 0x8000u;
    unsigned ub = __builtin_bit_cast(unsigned, b) + 0x8000u;
    return __builtin_amdgcn_perm(ub, ua, 0x07060302);
}

__device__ __forceinline__ void gl_lds16(const void* g, void* l) {
    __builtin_amdgcn_global_load_lds(
        (const __attribute__((address_space(1))) void*)g,
        (__attribute__((address_space(3))) void*)l, 16, 0, 0);
}

// ---------------------------------------------------------------------------
// Fused fp32 -> bf16 cast of [x | qkv_w | proj_w] into one contiguous region.
// ---------------------------------------------------------------------------
__global__ __launch_bounds__(256) void cast_all_bf16(
    const float* __restrict__ x, const float* __restrict__ qkvw,
    const float* __restrict__ pw, unsigned short* __restrict__ out) {
    int i = (blockIdx.x * 256 + threadIdx.x) * 8;
    const float* src;
    if (i < 4194304) src = x + i;
    else if (i < 7340032) src = qkvw + (i - 4194304);
    else src = pw + (i - 7340032);
    float4 v0 = *(const float4*)src;
    float4 v1 = *(const float4*)(src + 4);
    ushort8 r;
    r[0] = f2bf(v0.x); r[1] = f2bf(v0.y); r[2] = f2bf(v0.z); r[3] = f2bf(v0.w);
    r[4] = f2bf(v1.x); r[5] = f2bf(v1.y); r[6] = f2bf(v1.z); r[7] = f2bf(v1.w);
    *(ushort8*)(out + i) = r;
}

// ---------------------------------------------------------------------------
// Pack int32 mask (B,N,N) -> bitmask (B,N,N/64) uint64. One wave per word.
// ---------------------------------------------------------------------------
__global__ __launch_bounds__(256) void pack_mask(
    const int* __restrict__ mask, unsigned long long* __restrict__ bm) {
    int w = blockIdx.x * 4 + (threadIdx.x >> 6);
    int lane = threadIdx.x & 63;
    int mv = mask[(size_t)w * 64 + lane];
    unsigned long long bits = __ballot(mv != 0);
    if (lane == 0) bm[w] = bits;
}

// ---------------------------------------------------------------------------
// GEMM1 + fused LayerNorm epilogue.
// q/k are stored with a per-head d-permutation sigma(d) = (d&15)*4 + (d>>4)
// so each lane's 4 j-values are CONTIGUOUS (one uint2 store). sigma applied
// to both q and k leaves QK^T invariant (both MFMA operands permuted
// identically along the reduction dim). v is stored sigma-permuted too and
// un-permuted inside transpose_v.
// ---------------------------------------------------------------------------
__global__ __launch_bounds__(256) void gemm_qkv_ln(
    const unsigned short* __restrict__ A, const unsigned short* __restrict__ Bw,
    const float* __restrict__ qnw, const float* __restrict__ qnb,
    const float* __restrict__ knw, const float* __restrict__ knb,
    unsigned short* __restrict__ qbuf, unsigned short* __restrict__ kbuf,
    unsigned short* __restrict__ vbuf) {
    const int K = DIM_;
    __shared__ unsigned short As[128 * 32];
    __shared__ unsigned short Bs[128 * 32];
    const int tid = threadIdx.x;
    const int wave = tid >> 6, lane = tid & 63;
    const int quad = lane >> 4, lcol = lane & 15;
    const int wr = wave >> 1, wc = wave & 1;
    const int row0 = blockIdx.y * 128, col0 = blockIdx.x * 128;

    f32x4 acc[4][4];
#pragma unroll
    for (int i = 0; i < 4; ++i)
#pragma unroll
        for (int j = 0; j < 4; ++j) acc[i][j] = (f32x4){0.f, 0.f, 0.f, 0.f};

    for (int k0 = 0; k0 < K; k0 += 32) {
        __syncthreads();
#pragma unroll
        for (int c = 0; c < 2; ++c) {
            int base = wave * 2048 + c * 1024;
            int myofs = base + lane * 16;
            int r = myofs >> 6;
            int kb = myofs & 63;
            gl_lds16((const char*)A + ((size_t)(row0 + r) * K + k0) * 2 + kb,
                     (char*)As + base);
            gl_lds16((const char*)Bw + ((size_t)(col0 + r) * K + k0) * 2 + kb,
                     (char*)Bs + base);
        }
        __syncthreads();

        bf16x8 af[4], bfr[4];
#pragma unroll
        for (int i = 0; i < 4; ++i) {
            af[i] = *(const bf16x8*)&As[(wr * 64 + i * 16 + lcol) * 32 + quad * 8];
            bfr[i] = *(const bf16x8*)&Bs[(wc * 64 + i * 16 + lcol) * 32 + quad * 8];
        }
#pragma unroll
        for (int i = 0; i < 4; ++i)
#pragma unroll
            for (int j = 0; j < 4; ++j)
                acc[i][j] = __builtin_amdgcn_mfma_f32_16x16x32_bf16(
                    af[i], bfr[j], acc[i][j], 0, 0, 0);
    }

    const int colbase = col0 + wc * 64;      // wave-uniform, one head
    const int t = colbase >> 10;             // 0=q, 1=k, 2=v
    const int h = (colbase & 1023) >> 6;

    if (t < 2) {
        const float* wv = (t == 0) ? qnw : knw;
        const float* bv = (t == 0) ? qnb : knb;
        float wreg[4], breg[4];
#pragma unroll
        for (int j = 0; j < 4; ++j) {
            wreg[j] = wv[j * 16 + lcol];
            breg[j] = bv[j * 16 + lcol];
        }
        const float sc = (t == 0) ? (SCALE_ * LOG2E_) : 1.f;
        unsigned short* obase = (t == 0) ? qbuf : kbuf;
#pragma unroll
        for (int i = 0; i < 4; ++i) {
#pragma unroll
            for (int reg = 0; reg < 4; ++reg) {
                int row = row0 + wr * 64 + i * 16 + quad * 4 + reg;
                int bb = row >> 11, n = row & (N_ - 1);
                float v[4];
#pragma unroll
                for (int j = 0; j < 4; ++j) v[j] = acc[i][j][reg];
                float s = v[0] + v[1] + v[2] + v[3];
                s += __shfl_xor(s, 1);
                s += __shfl_xor(s, 2);
                s += __shfl_xor(s, 4);
                s += __shfl_xor(s, 8);
                float mu = s * (1.f / 64.f);
                float d[4], s2 = 0.f;
#pragma unroll
                for (int j = 0; j < 4; ++j) {
                    d[j] = v[j] - mu;
                    s2 += d[j] * d[j];
                }
                s2 += __shfl_xor(s2, 1);
                s2 += __shfl_xor(s2, 2);
                s2 += __shfl_xor(s2, 4);
                s2 += __shfl_xor(s2, 8);
                float r = rsqrtf(s2 * (1.f / 64.f) + EPS_);
                float o0 = (d[0] * r * wreg[0] + breg[0]) * sc;
                float o1 = (d[1] * r * wreg[1] + breg[1]) * sc;
                float o2 = (d[2] * r * wreg[2] + breg[2]) * sc;
                float o3 = (d[3] * r * wreg[3] + breg[3]) * sc;
                uint2 pk;
                pk.x = pk2bf(o0, o1);
                pk.y = pk2bf(o2, o3);
                // sigma store: positions lcol*4 + j, one uint2 per lane
                *(uint2*)(obase + ((size_t)(bb * H_ + h) * N_ + n) * 64 +
                          lcol * 4) = pk;
            }
        }
    } else {
#pragma unroll
        for (int i = 0; i < 4; ++i) {
#pragma unroll
            for (int reg = 0; reg < 4; ++reg) {
                int row = row0 + wr * 64 + i * 16 + quad * 4 + reg;
                uint2 pk;
                pk.x = pk2bf(acc[i][0][reg], acc[i][1][reg]);
                pk.y = pk2bf(acc[i][2][reg], acc[i][3][reg]);
                // sigma store within head span
                *(uint2*)(vbuf + (size_t)row * DIM_ + h * 64 + lcol * 4) = pk;
            }
        }
    }
}

// ---------------------------------------------------------------------------
// Output projection GEMM: C[4096,1024] = A[4096,1024] * Bw[1024,1024]^T + b.
// 128x64 tile -> 512 blocks (2/CU, vs 1/CU at 128x128). LDS 12 KB.
// Wave w handles rows w*32..w*32+31 (i in 2), all 64 cols (j in 4).
// ---------------------------------------------------------------------------
__global__ __launch_bounds__(256) void gemm_proj(
    const unsigned short* __restrict__ A, const unsigned short* __restrict__ Bw,
    const float* __restrict__ bias, float* __restrict__ Cout) {
    const int K = DIM_;
    __shared__ unsigned short As[128 * 32];  // 8 KB, 8 planes
    __shared__ unsigned short Bs[64 * 32];   // 4 KB, 4 planes
    const int tid = threadIdx.x;
    const int wave = tid >> 6, lane = tid & 63;
    const int quad = lane >> 4, lcol = lane & 15;
    const int row0 = blockIdx.y * 128, col0 = blockIdx.x * 64;

    f32x4 acc[2][4];
#pragma unroll
    for (int i = 0; i < 2; ++i)
#pragma unroll
        for (int j = 0; j < 4; ++j) acc[i][j] = (f32x4){0.f, 0.f, 0.f, 0.f};

    for (int k0 = 0; k0 < K; k0 += 32) {
        __syncthreads();
#pragma unroll
        for (int pi = 0; pi < 3; ++pi) {
            int p = wave * 3 + pi;  // 12 planes: 0..7 = A, 8..11 = B
            if (p < 8) {
                int base = p * 1024;
                int myofs = base + lane * 16;
                int r = myofs >> 6, kb = myofs & 63;
                gl_lds16((const char*)A + ((size_t)(row0 + r) * K + k0) * 2 + kb,
                         (char*)As + base);
            } else {
                int base = (p - 8) * 1024;
                int myofs = base + lane * 16;
                int r = myofs >> 6, kb = myofs & 63;
                gl_lds16((const char*)Bw + ((size_t)(col0 + r) * K + k0) * 2 + kb,
                         (char*)Bs + base);
            }
        }
        __syncthreads();

        bf16x8 af[2], bfr[4];
#pragma unroll
        for (int i = 0; i < 2; ++i)
            af[i] = *(const bf16x8*)&As[(wave * 32 + i * 16 + lcol) * 32 + quad * 8];
#pragma unroll
        for (int j = 0; j < 4; ++j)
            bfr[j] = *(const bf16x8*)&Bs[(j * 16 + lcol) * 32 + quad * 8];
#pragma unroll
        for (int i = 0; i < 2; ++i)
#pragma unroll
            for (int j = 0; j < 4; ++j)
                acc[i][j] = __builtin_amdgcn_mfma_f32_16x16x32_bf16(
                    af[i], bfr[j], acc[i][j], 0, 0, 0);
    }

#pragma unroll
    for (int i = 0; i < 2; ++i) {
#pragma unroll
        for (int j = 0; j < 4; ++j) {
            int col = col0 + j * 16 + lcol;
            float bv = bias[col];
#pragma unroll
            for (int reg = 0; reg < 4; ++reg) {
                int row = row0 + wave * 32 + i * 16 + quad * 4 + reg;
                Cout[(size_t)row * DIM_ + col] = acc[i][j][reg] + bv;
            }
        }
    }
}

// ---------------------------------------------------------------------------
// Extract V (bf16, sigma-permuted within head) from vbuf (B,N,H*D), write
// transposed (B,H,D,N) with PV-ready key permutation within each 64-key tile
// (see flash v6). sigma un-permute happens in the Ts write index.
// ---------------------------------------------------------------------------
__global__ __launch_bounds__(256) void transpose_v(
    const unsigned short* __restrict__ vbuf, unsigned short* __restrict__ vt) {
    __shared__ unsigned short Ts[64 * 65];
    const int tid = threadIdx.x;
    const int bh = blockIdx.y, n0 = blockIdx.x * 64;
    const int b = bh >> 4, h = bh & 15;
    {
        int r = tid >> 2, s = tid & 3;
        const unsigned short* src =
            vbuf + (size_t)(b * N_ + n0 + r) * DIM_ + h * 64 + s * 16;
#pragma unroll
        for (int i = 0; i < 16; ++i) {
            int p = s * 16 + i;                       // sigma position
            int trued = (p >> 2) + (p & 3) * 16;      // sigma^-1
            Ts[r * 65 + trued] = src[i];
        }
    }
    __syncthreads();
    {
        int d = tid >> 2, kt = tid & 3;  // 16 keys = one kt tile
        unsigned short* dstrow = vt + (size_t)(bh * 64 + d) * N_ + n0;
        int P = kt >> 1, t = kt & 1;
#pragma unroll
        for (int q = 0; q < 4; ++q) {
            __align__(8) unsigned short tmp4[4];
#pragma unroll
            for (int j = 0; j < 4; ++j)
                tmp4[j] = Ts[(kt * 16 + q * 4 + j) * 65 + d];
            *(uint2*)(dstrow + P * 32 + q * 8 + t * 4) = *(const uint2*)tmp4;
        }
    }
}

// ---------------------------------------------------------------------------
// MFMA flash attention v6 (unchanged from round 8): register-resident P,
// fixed-max softmax, double-buffered K/V, single barrier/iter.
// ---------------------------------------------------------------------------
__global__ __launch_bounds__(256) void flash_attn_mfma6(
    const unsigned short* __restrict__ q, const unsigned short* __restrict__ k,
    const unsigned short* __restrict__ vt,
    const unsigned long long* __restrict__ bm, unsigned short* __restrict__ ao) {
    __shared__ unsigned short Qs[64 * 64];        // 8 KB
    __shared__ unsigned short Ks[2][64 * 64];     // 16 KB, 8 planes/buf
    __shared__ unsigned short Vts[2][64 * 64];    // 16 KB, 8 planes/buf

    const int tid = threadIdx.x;
    const int wave = tid >> 6, lane = tid & 63;
    const int quad = lane >> 4, lcol = lane & 15;
    const int bh = blockIdx.y, b = bh >> 4, h = bh & 15;
    const int q0 = blockIdx.x * 64;

    const char* kgbase = (const char*)k + (size_t)bh * N_ * 128;
    const char* vtbase = (const char*)vt + (size_t)bh * 64 * N_ * 2;

    const char* kp[2];
    const char* vp[2];
#pragma unroll
    for (int ci = 0; ci < 2; ++ci) {
        int c = wave * 2 + ci;
        int swz = (c & 3) * 2;
        kp[ci] = kgbase + (size_t)(lane ^ swz) * 128 + c * 16;
        vp[ci] = vtbase + (size_t)(lane ^ swz) * N_ * 2 + c * 16;
    }

    {
        const char* qg = (const char*)(q + (size_t)(bh * N_ + q0) * 64);
#pragma unroll
        for (int c = 0; c < 2; ++c) {
            int base = wave * 2048 + c * 1024;
            gl_lds16(qg + base + lane * 16, (char*)Qs + base);
        }
#pragma unroll
        for (int ci = 0; ci < 2; ++ci) {
            int c = wave * 2 + ci;
            gl_lds16(kp[ci], (char*)Ks[0] + c * 1024);
            gl_lds16(vp[ci], (char*)Vts[0] + c * 1024);
            kp[ci] += 64 * 128;
            vp[ci] += 64 * 2;
        }
    }
    const unsigned long long* bmq =
        bm + ((size_t)b * N_ + q0 + wave * 16 + lcol) * 32;
    unsigned long long mw_next = bmq[0];
    __syncthreads();  // Q + tile0 resident

    bf16x8 bq[2];
#pragma unroll
    for (int d0 = 0; d0 < 2; ++d0)
        bq[d0] = *(const bf16x8*)&Qs[(wave * 16 + lcol) * 64 + d0 * 32 + quad * 8];

    ushort8 ot;
#pragma unroll
    for (int i = 0; i < 8; ++i) ot[i] = 0x3F80;  // bf16 1.0
    const bf16x8 ones = __builtin_bit_cast(bf16x8, ot);

    f32x4 oacc[4];
#pragma unroll
    for (int dt = 0; dt < 4; ++dt) oacc[dt] = (f32x4){0.f, 0.f, 0.f, 0.f};
    f32x4 lacc = (f32x4){0.f, 0.f, 0.f, 0.f};

    for (int k0 = 0; k0 < N_; k0 += 64) {
        const int cur = (k0 >> 6) & 1;
        const unsigned long long mw = mw_next;
        if (k0 + 64 < N_) {
#pragma unroll
            for (int ci = 0; ci < 2; ++ci) {
                int c = wave * 2 + ci;
                gl_lds16(kp[ci], (char*)Ks[cur ^ 1] + c * 1024);
                gl_lds16(vp[ci], (char*)Vts[cur ^ 1] + c * 1024);
                kp[ci] += 64 * 128;
                vp[ci] += 64 * 2;
            }
            mw_next = bmq[(k0 >> 6) + 1];
        }

        unsigned long long mq = mw >> (quad * 4);
        unsigned mlo = (unsigned)mq, mhi = (unsigned)(mq >> 32);
        f32x4 sacc[4];
#pragma unroll
        for (int kt = 0; kt < 4; ++kt) {
            unsigned word = (kt < 2) ? mlo : mhi;
            const int sh = (kt & 1) * 16;
#pragma unroll
            for (int reg = 0; reg < 4; ++reg)
                sacc[kt][reg] = ((word >> (sh + reg)) & 1u) ? -1e4f : -MFIX_;
        }

        const char* ksb = (const char*)Ks[cur];
        const char* vsb = (const char*)Vts[cur];
#pragma unroll
        for (int kt = 0; kt < 4; ++kt) {
#pragma unroll
            for (int d0 = 0; d0 < 2; ++d0) {
                int p = d0 * 4 + quad;
                bf16x8 ak = *(const bf16x8*)(ksb + p * 1024 +
                                             (((kt * 16 + lcol) ^ (quad * 2)) << 4));
                sacc[kt] = __builtin_amdgcn_mfma_f32_16x16x32_bf16(
                    ak, bq[d0], sacc[kt], 0, 0, 0);
            }
        }

        uint2 pk[4];
#pragma unroll
        for (int kt = 0; kt < 4; ++kt) {
            float p0 = exp2f(sacc[kt][0]);
            float p1 = exp2f(sacc[kt][1]);
            float p2 = exp2f(sacc[kt][2]);
            float p3 = exp2f(sacc[kt][3]);
            pk[kt].x = pk2bf(p0, p1);
            pk[kt].y = pk2bf(p2, p3);
        }

#pragma unroll
        for (int P = 0; P < 2; ++P) {
            uint4v bu;
            bu[0] = pk[2 * P].x;
            bu[1] = pk[2 * P].y;
            bu[2] = pk[2 * P + 1].x;
            bu[3] = pk[2 * P + 1].y;
            bf16x8 bp = __builtin_bit_cast(bf16x8, bu);
            lacc = __builtin_amdgcn_mfma_f32_16x16x32_bf16(ones, bp, lacc,
                                                           0, 0, 0);
#pragma unroll
            for (int dt = 0; dt < 4; ++dt) {
                int c = P * 4 + quad;
                bf16x8 va = *(const bf16x8*)(vsb + c * 1024 +
                                             (((dt * 16 + lcol) ^ (quad * 2)) << 4));
                oacc[dt] = __builtin_amdgcn_mfma_f32_16x16x32_bf16(
                    va, bp, oacc[dt], 0, 0, 0);
            }
        }
        __syncthreads();
    }

    float inv = 1.f / lacc[0];
    int row = q0 + wave * 16 + lcol;
    unsigned short* dst = ao + ((size_t)(b * N_ + row)) * DIM_ + h * 64 + quad * 4;
#pragma unroll
    for (int dt = 0; dt < 4; ++dt) {
        uint2 pko;
        pko.x = pk2bf(oacc[dt][0] * inv, oacc[dt][1] * inv);
        pko.y = pk2bf(oacc[dt][2] * inv, oacc[dt][3] * inv);
        *(uint2*)(dst + dt * 16) = pko;
    }
}

// ---------------------------------------------------------------------------
extern "C" void kernel_launch(void* const* d_in, const int* in_sizes, int n_in,
                              void* d_out, int out_size, void* d_ws,
                              size_t ws_size, hipStream_t stream) {
    const float* x     = (const float*)d_in[0];
    const int*   mask  = (const int*)d_in[1];
    const float* qkv_w = (const float*)d_in[2];
    const float* qnw   = (const float*)d_in[3];
    const float* qnb   = (const float*)d_in[4];
    const float* knw   = (const float*)d_in[5];
    const float* knb   = (const float*)d_in[6];
    const float* pw    = (const float*)d_in[7];
    const float* pb    = (const float*)d_in[8];
    float* out = (float*)d_out;

    // workspace layout (bytes) — 51.4 MB total
    char* ws = (char*)d_ws;
    unsigned short* x_bf  = (unsigned short*)(ws + 0);          // 8.39 MB
    unsigned short* qw_bf = (unsigned short*)(ws + 8388608);    // 6.29 MB
    unsigned short* pw_bf = (unsigned short*)(ws + 14680064);   // 2.10 MB
    unsigned short* qbuf  = (unsigned short*)(ws + 16777216);   // 8.39 MB
    unsigned short* kbuf  = (unsigned short*)(ws + 25165824);   // 8.39 MB
    unsigned short* vbuf  = (unsigned short*)(ws + 33554432);   // 8.39 MB
    unsigned short* vt    = (unsigned short*)(ws + 41943040);   // 8.39 MB
    unsigned long long* bmask = (unsigned long long*)(ws + 50331648);  // 1 MB
    unsigned short* ao_bnc = vbuf;  // alias: vbuf dead after transpose_v

    // 0) fused casts -> contiguous [x_bf | qw_bf | pw_bf]
    cast_all_bf16<<<8388608 / 2048, 256, 0, stream>>>(x, qkv_w, pw, x_bf);

    // 1) GEMM1 + fused LN epilogue -> qbuf/kbuf (B,H,N,D) sigma-d, vbuf
    gemm_qkv_ln<<<dim3(3072 / 128, 4096 / 128), 256, 0, stream>>>(
        x_bf, qw_bf, qnw, qnb, knw, knb, qbuf, kbuf, vbuf);

    // 2) v -> bf16 transposed + key-permuted (B,H,D,N)
    transpose_v<<<dim3(N_ / 64, B_ * H_), 256, 0, stream>>>(vbuf, vt);

    // 2b) pack mask to bits
    pack_mask<<<(B_ * N_ * (N_ / 64)) / 4, 256, 0, stream>>>(mask, bmask);

    // 3) masked flash attention v6 -> ao bf16 (B,N,C)
    flash_attn_mfma6<<<dim3(N_ / 64, B_ * H_), 256, 0, stream>>>(
        qbuf, kbuf, vt, bmask, ao_bnc);

    // 4) out = ao @ proj_w^T + proj_b (128x64 tile, 2 blocks/CU)
    gemm_proj<<<dim3(DIM_ / 64, 4096 / 128), 256, 0, stream>>>(
        ao_bnc, pw_bf, pb, out);
}